// Round 2
// baseline (578.707 us; speedup 1.0000x reference)
//
#include <hip/hip_runtime.h>
#include <math.h>

#define BB 8
#define HH 512
#define WW 512
#define NPIX (BB * HH * WW)        // 2097152
#define HWPIX (HH * WW)            // 262144 = 2^18
#define PBUD 1048576               // P
#define RAD 7                      // 15//2
#define NB (NPIX / 256)            // 8192 blocks of 256 pixels

// ---------------- K0: transpose W2 (128x128) -> w2t[j*128+k] = w2[k*128+j] ----
__global__ void k_tr_w2(const float* __restrict__ w2, float* __restrict__ w2t) {
    int i = blockIdx.x * 256 + threadIdx.x;   // 16384 threads
    int k = i >> 7;
    int j = i & 127;
    w2t[j * 128 + k] = w2[i];
}

// ---------------- K1: mask + horizontal dilate --------------------------------
__global__ void k_rowdil(const float* __restrict__ lr, unsigned char* __restrict__ rowdil) {
    int p = blockIdx.x * 256 + threadIdx.x;
    int w = p & (WW - 1);
    int row0 = p - w;
    int lo = w - RAD; if (lo < 0) lo = 0;
    int hi = w + RAD; if (hi > WW - 1) hi = WW - 1;
    unsigned char any = 0;
    for (int x = lo; x <= hi; ++x) {
        float v = lr[row0 + x];
        any |= (unsigned char)(v > 0.01f && v < 0.99f);
    }
    rowdil[p] = any;
}

// ---------------- K2: vertical dilate + per-block mask count ------------------
__global__ void k_coldil(const unsigned char* __restrict__ rowdil,
                         unsigned char* __restrict__ dm,
                         int* __restrict__ gsum) {
    int p = blockIdx.x * 256 + threadIdx.x;
    int h = (p >> 9) & (HH - 1);
    int lo = h - RAD; if (lo < 0) lo = 0;
    int hi = h + RAD; if (hi > HH - 1) hi = HH - 1;
    lo -= h; hi -= h;
    unsigned char any = 0;
    for (int d = lo; d <= hi; ++d) any |= rowdil[p + d * WW];
    dm[p] = any;

    unsigned long long bal = __ballot(any != 0);
    __shared__ int wsum[4];
    int lane = threadIdx.x & 63;
    int wid  = threadIdx.x >> 6;
    if (lane == 0) wsum[wid] = __popcll(bal);
    __syncthreads();
    if (threadIdx.x == 0) gsum[blockIdx.x] = wsum[0] + wsum[1] + wsum[2] + wsum[3];
}

// ---------------- K3: exclusive scan of 8192 block counts (one block) ---------
__global__ void k_scan(const int* __restrict__ gsum, int* __restrict__ goff) {
    __shared__ int tsum[1024];
    int t = threadIdx.x;
    int base = t * 8;
    int v[8];
    int s = 0;
#pragma unroll
    for (int i = 0; i < 8; ++i) { v[i] = gsum[base + i]; s += v[i]; }
    tsum[t] = s;
    __syncthreads();
    // Hillis-Steele inclusive scan over 1024 partials
    for (int off = 1; off < 1024; off <<= 1) {
        int x = tsum[t];
        int y = (t >= off) ? tsum[t - off] : 0;
        __syncthreads();
        tsum[t] = x + y;
        __syncthreads();
    }
    int run = (t == 0) ? 0 : tsum[t - 1];
#pragma unroll
    for (int i = 0; i < 8; ++i) { goff[base + i] = run; run += v[i]; }
}

// ---------------- K4: rank + per-pixel MLP ------------------------------------
__global__ __launch_bounds__(256)
void k_mlp(const float* __restrict__ image, const float* __restrict__ lr,
           const float* __restrict__ w1, const float* __restrict__ b1,
           const float* __restrict__ w2t, const float* __restrict__ b2,
           const float* __restrict__ w3, const float* __restrict__ b3,
           const unsigned char* __restrict__ dm, const int* __restrict__ goff,
           float* __restrict__ out) {
    int p = blockIdx.x * 256 + threadIdx.x;
    unsigned char m = dm[p];
    float lrv = lr[p];

    // intra-block rank of masked pixels
    unsigned long long bal = __ballot(m != 0);
    int lane = threadIdx.x & 63;
    int wid  = threadIdx.x >> 6;
    __shared__ int wsum[4];
    if (lane == 0) wsum[wid] = __popcll(bal);
    __syncthreads();
    int pre = __popcll(bal & ((1ull << lane) - 1ull));
    int woff = 0;
    for (int i = 0; i < wid; ++i) woff += wsum[i];
    int rank = goff[blockIdx.x] + woff + pre;

    bool sel = (m != 0) && (rank < PBUD);
    if (!sel) { out[p] = lrv; return; }

    // gather features: [img_c0, img_c1, img_c2, 2*lr-1]
    int hw = p & (HWPIX - 1);
    int b  = p >> 18;
    const float* img = image + (size_t)b * 3 * HWPIX + hw;
    float x0 = img[0];
    float x1 = img[HWPIX];
    float x2 = img[2 * HWPIX];
    float x3 = 2.0f * lrv - 1.0f;

    // layer 1: 4 -> 128
    float h1[128];
#pragma unroll
    for (int j = 0; j < 128; ++j) {
        float a = b1[j];
        a = fmaf(x0, w1[j], a);
        a = fmaf(x1, w1[128 + j], a);
        a = fmaf(x2, w1[256 + j], a);
        a = fmaf(x3, w1[384 + j], a);
        h1[j] = fmaxf(a, 0.0f);
    }

    // layer 2 (128 -> 128) fused with layer 3 (128 -> 1)
    float logit = b3[0];
    for (int j = 0; j < 128; ++j) {
        const float* wr = w2t + j * 128;   // wave-uniform row -> scalar loads
        float a0 = 0.f, a1 = 0.f, a2 = 0.f, a3 = 0.f;
#pragma unroll
        for (int k = 0; k < 128; k += 4) {
            a0 = fmaf(h1[k + 0], wr[k + 0], a0);
            a1 = fmaf(h1[k + 1], wr[k + 1], a1);
            a2 = fmaf(h1[k + 2], wr[k + 2], a2);
            a3 = fmaf(h1[k + 3], wr[k + 3], a3);
        }
        float acc = b2[j] + ((a0 + a1) + (a2 + a3));
        float h2 = fmaxf(acc, 0.0f);
        logit = fmaf(h2, w3[j], logit);
    }

    out[p] = 1.0f / (1.0f + __expf(-logit));
}

// ---------------- launcher ----------------------------------------------------
extern "C" void kernel_launch(void* const* d_in, const int* in_sizes, int n_in,
                              void* d_out, int out_size, void* d_ws, size_t ws_size,
                              hipStream_t stream) {
    const float* image = (const float*)d_in[0];
    const float* lr    = (const float*)d_in[1];
    const float* w1    = (const float*)d_in[2];
    const float* b1    = (const float*)d_in[3];
    const float* w2    = (const float*)d_in[4];
    const float* b2    = (const float*)d_in[5];
    const float* w3    = (const float*)d_in[6];
    const float* b3    = (const float*)d_in[7];
    float* out = (float*)d_out;

    char* ws = (char*)d_ws;
    unsigned char* rowdil = (unsigned char*)ws;                    // NPIX bytes
    unsigned char* dm     = (unsigned char*)(ws + NPIX);           // NPIX bytes
    int*   gsum = (int*)(ws + 2 * (size_t)NPIX);                   // NB ints
    int*   goff = (int*)(ws + 2 * (size_t)NPIX + NB * 4);          // NB ints
    float* w2t  = (float*)(ws + 2 * (size_t)NPIX + 2 * NB * 4);    // 16384 floats

    k_tr_w2 <<<64, 256, 0, stream>>>(w2, w2t);
    k_rowdil<<<NPIX / 256, 256, 0, stream>>>(lr, rowdil);
    k_coldil<<<NB, 256, 0, stream>>>(rowdil, dm, gsum);
    k_scan  <<<1, 1024, 0, stream>>>(gsum, goff);
    k_mlp   <<<NB, 256, 0, stream>>>(image, lr, w1, b1, w2t, b2, w3, b3, dm, goff, out);
}

// Round 4
// 234.300 us; speedup vs baseline: 2.4699x; 2.4699x over previous
//
#include <hip/hip_runtime.h>
#include <math.h>

#define BB 8
#define HH 512
#define WW 512
#define NPIX (BB * HH * WW)        // 2097152
#define HWPIX (HH * WW)            // 262144 = 2^18
#define PBUD 1048576               // P
#define RAD 7                      // 15//2
#define NB (NPIX / 256)            // 8192 rank blocks of 256 pixels
#define NMLP (NPIX / 128)          // 16384 MLP blocks of 128 pixels

typedef __attribute__((ext_vector_type(4))) float f32x4;
typedef __attribute__((ext_vector_type(8))) short short8;

__device__ __forceinline__ unsigned short f2bf(float f) {
    unsigned int u = __float_as_uint(f);
    unsigned int r = (u + 0x7fffu + ((u >> 16) & 1u)) >> 16;   // RNE
    return (unsigned short)r;
}

// ---------------- K0: W2 [k][j] fp32 -> W2^T [j][k] bf16 ----------------------
__global__ void k_prep_w2(const float* __restrict__ w2, unsigned short* __restrict__ w2tb) {
    int i = blockIdx.x * 256 + threadIdx.x;   // 16384 threads
    int k = i >> 7;
    int j = i & 127;
    w2tb[j * 128 + k] = f2bf(w2[i]);
}

// ---------------- K1: mask + horizontal dilate --------------------------------
__global__ void k_rowdil(const float* __restrict__ lr, unsigned char* __restrict__ rowdil) {
    int p = blockIdx.x * 256 + threadIdx.x;
    int w = p & (WW - 1);
    int row0 = p - w;
    int lo = w - RAD; if (lo < 0) lo = 0;
    int hi = w + RAD; if (hi > WW - 1) hi = WW - 1;
    unsigned char any = 0;
    for (int x = lo; x <= hi; ++x) {
        float v = lr[row0 + x];
        any |= (unsigned char)(v > 0.01f && v < 0.99f);
    }
    rowdil[p] = any;
}

// ------- K2: vertical dilate + per-256-block count + intra-block rank byte ----
__global__ void k_coldil(const unsigned char* __restrict__ rowdil,
                         unsigned char* __restrict__ dm,
                         unsigned char* __restrict__ rankb,
                         int* __restrict__ gsum) {
    int p = blockIdx.x * 256 + threadIdx.x;
    int h = (p >> 9) & (HH - 1);
    int lo = h - RAD; if (lo < 0) lo = 0;
    int hi = h + RAD; if (hi > HH - 1) hi = HH - 1;
    lo -= h; hi -= h;
    unsigned char any = 0;
    for (int d = lo; d <= hi; ++d) any |= rowdil[p + d * WW];
    dm[p] = any;

    unsigned long long bal = __ballot(any != 0);
    __shared__ int wsum[4];
    int lane = threadIdx.x & 63;
    int wid  = threadIdx.x >> 6;
    if (lane == 0) wsum[wid] = __popcll(bal);
    __syncthreads();
    int pre = __popcll(bal & ((1ull << lane) - 1ull));
    int woff = 0;
    for (int i = 0; i < wid; ++i) woff += wsum[i];
    rankb[p] = (unsigned char)(woff + pre);
    if (threadIdx.x == 0) gsum[blockIdx.x] = wsum[0] + wsum[1] + wsum[2] + wsum[3];
}

// ---------------- K3: exclusive scan of 8192 block counts (one block) ---------
__global__ void k_scan(const int* __restrict__ gsum, int* __restrict__ goff) {
    __shared__ int tsum[1024];
    int t = threadIdx.x;
    int base = t * 8;
    int v[8];
    int s = 0;
#pragma unroll
    for (int i = 0; i < 8; ++i) { v[i] = gsum[base + i]; s += v[i]; }
    tsum[t] = s;
    __syncthreads();
    for (int off = 1; off < 1024; off <<= 1) {
        int x = tsum[t];
        int y = (t >= off) ? tsum[t - off] : 0;
        __syncthreads();
        tsum[t] = x + y;
        __syncthreads();
    }
    int run = (t == 0) ? 0 : tsum[t - 1];
#pragma unroll
    for (int i = 0; i < 8; ++i) { goff[base + i] = run; run += v[i]; }
}

// ---------------- K4: MFMA MLP over 128-pixel tiles ---------------------------
// LDS: [0,32768)  H1 tile, 128 rows x 128 bf16 (256B rows), XOR-swizzled
//      [32768,65536) W2^T tile, 128 rows (out-dim j) x 128 bf16, XOR-swizzled
// swizzle: byte ^= (row & 15) << 4   (bijective within each 256B row)
__global__ __launch_bounds__(256)
void k_mlp(const float* __restrict__ image, const float* __restrict__ lr,
           const float* __restrict__ w1, const float* __restrict__ b1,
           const unsigned short* __restrict__ w2tb, const float* __restrict__ b2,
           const float* __restrict__ w3, const float* __restrict__ b3,
           const unsigned char* __restrict__ dm, const unsigned char* __restrict__ rankb,
           const int* __restrict__ goff, float* __restrict__ out) {
    __shared__ __align__(16) char lds[65536];
    int g  = blockIdx.x;
    int p0 = g * 128;
    int t  = threadIdx.x;

    // ---- phase 0: any selected pixel in this 128-px tile? ----
    if (t == 0) *(volatile int*)lds = 0;
    __syncthreads();
    if (t < 128) {
        int p = p0 + t;
        bool s = dm[p] && (goff[p >> 8] + (int)rankb[p] < PBUD);
        if (s) *(volatile int*)lds = 1;
    }
    __syncthreads();
    int any = *(volatile int*)lds;
    __syncthreads();                       // protect lds[0] read before H1 writes
    if (!any) {
        if (t < 128) out[p0 + t] = lr[p0 + t];
        return;
    }

    // ---- phase 1a: stage W2^T bf16 -> LDS (swizzled) ----
    {
        const short8* wsrc = (const short8*)w2tb;
        int row = t >> 1;
#pragma unroll
        for (int i = 0; i < 8; ++i) {
            int c = (t & 1) * 8 + i;
            short8 v = wsrc[row * 16 + c];
            int a = 32768 + ((((row << 8) | (c << 4))) ^ ((row & 15) << 4));
            *(short8*)(lds + a) = v;
        }
    }

    // ---- phase 1b: layer 1 (4 -> 128) -> bf16 H1 in LDS (swizzled) ----
    {
        int px = t & 127;                  // pixel row in tile
        int jh = t >> 7;                   // 0: j in [0,64), 1: j in [64,128)  (wave-uniform)
        int p  = p0 + px;
        float lrv = lr[p];
        size_t bimg = (size_t)(p >> 18) * 3 * HWPIX + (p & (HWPIX - 1));
        float x0 = image[bimg];
        float x1 = image[bimg + HWPIX];
        float x2 = image[bimg + 2 * HWPIX];
        float x3 = 2.0f * lrv - 1.0f;
#pragma unroll
        for (int jc8 = 0; jc8 < 8; ++jc8) {
            int jc = jh * 8 + jc8;         // 16B chunk index (8 bf16)
            unsigned short hv[8];
#pragma unroll
            for (int e = 0; e < 8; ++e) {
                int j = jc * 8 + e;        // wave-uniform -> s_load broadcast of w1/b1
                float a = b1[j];
                a = fmaf(x0, w1[j], a);
                a = fmaf(x1, w1[128 + j], a);
                a = fmaf(x2, w1[256 + j], a);
                a = fmaf(x3, w1[384 + j], a);
                hv[e] = f2bf(fmaxf(a, 0.0f));
            }
            short8 pk;
#pragma unroll
            for (int e = 0; e < 8; ++e) pk[e] = (short)hv[e];
            int a = (((px << 8) | (jc << 4))) ^ ((px & 15) << 4);
            *(short8*)(lds + a) = pk;
        }
    }
    __syncthreads();

    // ---- phase 2: wave w computes rows [w*32, w*32+32) x all 128 cols ----
    int w    = t >> 6;
    int l    = t & 63;
    int lr16 = l & 15;
    int lh   = l >> 4;
    int rowbase = w * 32;

    f32x4 acc[2][8];
#pragma unroll
    for (int mt = 0; mt < 2; ++mt)
#pragma unroll
        for (int jc = 0; jc < 8; ++jc) acc[mt][jc] = (f32x4){0.f, 0.f, 0.f, 0.f};

#pragma unroll
    for (int ks = 0; ks < 4; ++ks) {
        short8 af[2];
#pragma unroll
        for (int mt = 0; mt < 2; ++mt) {
            int row = rowbase + mt * 16 + lr16;
            int a = (((row << 8) | (ks << 6) | (lh << 4))) ^ ((row & 15) << 4);
            af[mt] = *(const short8*)(lds + a);
        }
#pragma unroll
        for (int jc = 0; jc < 8; ++jc) {
            int rb = jc * 16 + lr16;       // W2^T row = output dim
            int a = 32768 + ((((rb << 8) | (ks << 6) | (lh << 4))) ^ ((rb & 15) << 4));
            short8 bf = *(const short8*)(lds + a);
            acc[0][jc] = __builtin_amdgcn_mfma_f32_16x16x32_bf16(af[0], bf, acc[0][jc], 0, 0, 0);
            acc[1][jc] = __builtin_amdgcn_mfma_f32_16x16x32_bf16(af[1], bf, acc[1][jc], 0, 0, 0);
        }
    }

    // ---- epilogue: bias + relu + dot(w3) reduce + sigmoid + select ----
    float b2v[8], w3v[8];
#pragma unroll
    for (int jc = 0; jc < 8; ++jc) {
        int col = jc * 16 + lr16;
        b2v[jc] = b2[col];
        w3v[jc] = w3[col];
    }
    float b3v = b3[0];

#pragma unroll
    for (int mt = 0; mt < 2; ++mt) {
#pragma unroll
        for (int r = 0; r < 4; ++r) {
            int row = rowbase + mt * 16 + lh * 4 + r;   // row depends on lh only
            float part = 0.f;
#pragma unroll
            for (int jc = 0; jc < 8; ++jc)
                part += fmaxf(acc[mt][jc][r] + b2v[jc], 0.f) * w3v[jc];
            part += __shfl_xor(part, 1);
            part += __shfl_xor(part, 2);
            part += __shfl_xor(part, 4);
            part += __shfl_xor(part, 8);
            if (lr16 == 0) {
                int p = p0 + row;
                float lrv = lr[p];
                bool s = dm[p] && (goff[p >> 8] + (int)rankb[p] < PBUD);
                float logit = b3v + part;
                out[p] = s ? (1.0f / (1.0f + __expf(-logit))) : lrv;
            }
        }
    }
}

// ---------------- launcher ----------------------------------------------------
extern "C" void kernel_launch(void* const* d_in, const int* in_sizes, int n_in,
                              void* d_out, int out_size, void* d_ws, size_t ws_size,
                              hipStream_t stream) {
    const float* image = (const float*)d_in[0];
    const float* lr    = (const float*)d_in[1];
    const float* w1    = (const float*)d_in[2];
    const float* b1    = (const float*)d_in[3];
    const float* w2    = (const float*)d_in[4];
    const float* b2    = (const float*)d_in[5];
    const float* w3    = (const float*)d_in[6];
    const float* b3    = (const float*)d_in[7];
    float* out = (float*)d_out;

    char* ws = (char*)d_ws;
    unsigned char* rowdil = (unsigned char*)ws;                         // NPIX
    unsigned char* dm     = (unsigned char*)(ws + (size_t)NPIX);        // NPIX
    unsigned char* rankb  = (unsigned char*)(ws + 2 * (size_t)NPIX);    // NPIX
    int* gsum             = (int*)(ws + 3 * (size_t)NPIX);              // NB
    int* goff             = (int*)(ws + 3 * (size_t)NPIX + NB * 4);     // NB
    unsigned short* w2tb  = (unsigned short*)(ws + 3 * (size_t)NPIX + 2 * NB * 4); // 16384 bf16

    k_prep_w2<<<64, 256, 0, stream>>>(w2, w2tb);
    k_rowdil <<<NPIX / 256, 256, 0, stream>>>(lr, rowdil);
    k_coldil <<<NB, 256, 0, stream>>>(rowdil, dm, rankb, gsum);
    k_scan   <<<1, 1024, 0, stream>>>(gsum, goff);
    k_mlp    <<<NMLP, 256, 0, stream>>>(image, lr, w1, b1, w2tb, b2, w3, b3,
                                        dm, rankb, goff, out);
}

// Round 5
// 135.339 us; speedup vs baseline: 4.2760x; 1.7312x over previous
//
#include <hip/hip_runtime.h>
#include <math.h>

#define BB 8
#define HH 512
#define WW 512
#define NPIX (BB * HH * WW)        // 2097152
#define HWPIX (HH * WW)            // 262144 = 2^18
#define PBUD 1048576               // P
#define RAD 7                      // 15//2
#define NB (NPIX / 256)            // 8192 rank blocks of 256 pixels
#define NMLP (NPIX / 128)          // 16384 MLP blocks of 128 pixels

typedef __attribute__((ext_vector_type(4))) float f32x4;
typedef __attribute__((ext_vector_type(8))) short short8;

__device__ __forceinline__ unsigned short f2bf(float f) {
    unsigned int u = __float_as_uint(f);
    unsigned int r = (u + 0x7fffu + ((u >> 16) & 1u)) >> 16;   // RNE
    return (unsigned short)r;
}

// ---- K0: W2 [k][j] fp32 -> bf16 B-fragments in exact MFMA lane order --------
// w2f[((jc*4+ks)*64 + lane)*8 + e] = bf16( W2[k][j] ),
//   j = jc*16 + (lane&15),  k = ks*32 + ((lane>>4)&3)*8 + e
__global__ void k_prep_w2(const float* __restrict__ w2, unsigned short* __restrict__ w2f) {
    int i = blockIdx.x * 256 + threadIdx.x;   // 16384 threads
    int e  = i & 7;
    int l  = (i >> 3) & 63;
    int ks = (i >> 9) & 3;
    int jc = i >> 11;
    int j = jc * 16 + (l & 15);
    int k = ks * 32 + ((l >> 4) & 3) * 8 + e;
    w2f[i] = f2bf(w2[k * 128 + j]);
}

// ---------------- K1: mask + horizontal dilate --------------------------------
__global__ void k_rowdil(const float* __restrict__ lr, unsigned char* __restrict__ rowdil) {
    int p = blockIdx.x * 256 + threadIdx.x;
    int w = p & (WW - 1);
    int row0 = p - w;
    int lo = w - RAD; if (lo < 0) lo = 0;
    int hi = w + RAD; if (hi > WW - 1) hi = WW - 1;
    unsigned char any = 0;
    for (int x = lo; x <= hi; ++x) {
        float v = lr[row0 + x];
        any |= (unsigned char)(v > 0.01f && v < 0.99f);
    }
    rowdil[p] = any;
}

// ------- K2: vertical dilate + per-256-block count + intra-block rank byte ----
__global__ void k_coldil(const unsigned char* __restrict__ rowdil,
                         unsigned char* __restrict__ dm,
                         unsigned char* __restrict__ rankb,
                         int* __restrict__ gsum) {
    int p = blockIdx.x * 256 + threadIdx.x;
    int h = (p >> 9) & (HH - 1);
    int lo = h - RAD; if (lo < 0) lo = 0;
    int hi = h + RAD; if (hi > HH - 1) hi = HH - 1;
    lo -= h; hi -= h;
    unsigned char any = 0;
    for (int d = lo; d <= hi; ++d) any |= rowdil[p + d * WW];
    dm[p] = any;

    unsigned long long bal = __ballot(any != 0);
    __shared__ int wsum[4];
    int lane = threadIdx.x & 63;
    int wid  = threadIdx.x >> 6;
    if (lane == 0) wsum[wid] = __popcll(bal);
    __syncthreads();
    int pre = __popcll(bal & ((1ull << lane) - 1ull));
    int woff = 0;
    for (int i = 0; i < wid; ++i) woff += wsum[i];
    rankb[p] = (unsigned char)(woff + pre);
    if (threadIdx.x == 0) gsum[blockIdx.x] = wsum[0] + wsum[1] + wsum[2] + wsum[3];
}

// ---------------- K3: exclusive scan of 8192 block counts (one block) ---------
__global__ void k_scan(const int* __restrict__ gsum, int* __restrict__ goff) {
    __shared__ int tsum[1024];
    int t = threadIdx.x;
    int base = t * 8;
    int v[8];
    int s = 0;
#pragma unroll
    for (int i = 0; i < 8; ++i) { v[i] = gsum[base + i]; s += v[i]; }
    tsum[t] = s;
    __syncthreads();
    for (int off = 1; off < 1024; off <<= 1) {
        int x = tsum[t];
        int y = (t >= off) ? tsum[t - off] : 0;
        __syncthreads();
        tsum[t] = x + y;
        __syncthreads();
    }
    int run = (t == 0) ? 0 : tsum[t - 1];
#pragma unroll
    for (int i = 0; i < 8; ++i) { goff[base + i] = run; run += v[i]; }
}

// ---------------- K4: MFMA MLP over 128-pixel tiles ---------------------------
// LDS: H1 tile only — 128 rows x 128 bf16 (256B rows), XOR-swizzled:
//   byte ^= (row & 15) << 4   (bijective within each 256B row)
// B-operand comes straight from global w2f (L2-resident, fragment-ordered).
__global__ __launch_bounds__(256, 3)
void k_mlp(const float* __restrict__ image, const float* __restrict__ lr,
           const float* __restrict__ w1, const float* __restrict__ b1,
           const unsigned short* __restrict__ w2f, const float* __restrict__ b2,
           const float* __restrict__ w3, const float* __restrict__ b3,
           const unsigned char* __restrict__ dm, const unsigned char* __restrict__ rankb,
           const int* __restrict__ goff, float* __restrict__ out) {
    __shared__ __align__(16) char lds[32768];
    __shared__ int s_any;
    int g  = blockIdx.x;
    int p0 = g * 128;
    int t  = threadIdx.x;

    // ---- phase 0: any selected pixel in this 128-px tile? ----
    if (t == 0) s_any = 0;
    __syncthreads();
    if (t < 128) {
        int p = p0 + t;
        if (dm[p] && (goff[p >> 8] + (int)rankb[p] < PBUD)) s_any = 1;
    }
    __syncthreads();
    if (!s_any) {
        if (t < 128) out[p0 + t] = lr[p0 + t];
        return;
    }

    // ---- phase 1: layer 1 (4 -> 128) -> bf16 H1 in LDS (swizzled) ----
    {
        int px = t & 127;                  // pixel row in tile
        // readfirstlane -> SGPR: makes all w1/b1 addresses provably uniform
        // so the backend emits s_load (scalar K$ broadcast), not 320 VMEM loads.
        int jh = __builtin_amdgcn_readfirstlane(t >> 7);   // 0 or 1, wave-uniform
        int p  = p0 + px;
        float lrv = lr[p];
        size_t bimg = (size_t)(p >> 18) * 3 * HWPIX + (p & (HWPIX - 1));
        float x0 = image[bimg];
        float x1 = image[bimg + HWPIX];
        float x2 = image[bimg + 2 * HWPIX];
        float x3 = 2.0f * lrv - 1.0f;
#pragma unroll
        for (int jc8 = 0; jc8 < 8; ++jc8) {
            int jc = jh * 8 + jc8;         // 16B chunk index (8 bf16)
            unsigned short hv[8];
#pragma unroll
            for (int e = 0; e < 8; ++e) {
                int j = jc * 8 + e;        // SGPR-computable -> s_load
                float a = b1[j];
                a = fmaf(x0, w1[j], a);
                a = fmaf(x1, w1[128 + j], a);
                a = fmaf(x2, w1[256 + j], a);
                a = fmaf(x3, w1[384 + j], a);
                hv[e] = f2bf(fmaxf(a, 0.0f));
            }
            short8 pk;
#pragma unroll
            for (int e = 0; e < 8; ++e) pk[e] = (short)hv[e];
            int a = (((px << 8) | (jc << 4))) ^ ((px & 15) << 4);
            *(short8*)(lds + a) = pk;
        }
    }
    __syncthreads();

    // ---- phase 2: wave w computes rows [w*32, w*32+32) x all 128 cols ----
    int w    = t >> 6;
    int l    = t & 63;
    int lr16 = l & 15;
    int lh   = l >> 4;
    int rowbase = w * 32;

    // A-fragments from LDS (verified layout from round 4)
    short8 af[2][4];
#pragma unroll
    for (int ks = 0; ks < 4; ++ks) {
#pragma unroll
        for (int mt = 0; mt < 2; ++mt) {
            int row = rowbase + mt * 16 + lr16;
            int a = (((row << 8) | (ks << 6) | (lh << 4))) ^ ((row & 15) << 4);
            af[mt][ks] = *(const short8*)(lds + a);
        }
    }

    f32x4 acc[2][8];
#pragma unroll
    for (int mt = 0; mt < 2; ++mt)
#pragma unroll
        for (int jc = 0; jc < 8; ++jc) acc[mt][jc] = (f32x4){0.f, 0.f, 0.f, 0.f};

    const short8* wf = (const short8*)w2f;
#pragma unroll
    for (int jc = 0; jc < 8; ++jc) {
        short8 bf[4];
#pragma unroll
        for (int ks = 0; ks < 4; ++ks) bf[ks] = wf[(jc * 4 + ks) * 64 + l];  // coalesced, L2-hot
#pragma unroll
        for (int ks = 0; ks < 4; ++ks) {
            acc[0][jc] = __builtin_amdgcn_mfma_f32_16x16x32_bf16(af[0][ks], bf[ks], acc[0][jc], 0, 0, 0);
            acc[1][jc] = __builtin_amdgcn_mfma_f32_16x16x32_bf16(af[1][ks], bf[ks], acc[1][jc], 0, 0, 0);
        }
    }

    // ---- epilogue: bias + relu + dot(w3) reduce + sigmoid + select ----
    float b2v[8], w3v[8];
#pragma unroll
    for (int jc = 0; jc < 8; ++jc) {
        int col = jc * 16 + lr16;
        b2v[jc] = b2[col];
        w3v[jc] = w3[col];
    }
    float b3v = b3[0];

#pragma unroll
    for (int mt = 0; mt < 2; ++mt) {
#pragma unroll
        for (int r = 0; r < 4; ++r) {
            int row = rowbase + mt * 16 + lh * 4 + r;   // C/D layout: row = (lane>>4)*4 + reg
            float part = 0.f;
#pragma unroll
            for (int jc = 0; jc < 8; ++jc)
                part += fmaxf(acc[mt][jc][r] + b2v[jc], 0.f) * w3v[jc];
            part += __shfl_xor(part, 1);
            part += __shfl_xor(part, 2);
            part += __shfl_xor(part, 4);
            part += __shfl_xor(part, 8);
            if (lr16 == 0) {
                int p = p0 + row;
                float lrv = lr[p];
                bool s = dm[p] && (goff[p >> 8] + (int)rankb[p] < PBUD);
                float logit = b3v + part;
                out[p] = s ? (1.0f / (1.0f + __expf(-logit))) : lrv;
            }
        }
    }
}

// ---------------- launcher ----------------------------------------------------
extern "C" void kernel_launch(void* const* d_in, const int* in_sizes, int n_in,
                              void* d_out, int out_size, void* d_ws, size_t ws_size,
                              hipStream_t stream) {
    const float* image = (const float*)d_in[0];
    const float* lr    = (const float*)d_in[1];
    const float* w1    = (const float*)d_in[2];
    const float* b1    = (const float*)d_in[3];
    const float* w2    = (const float*)d_in[4];
    const float* b2    = (const float*)d_in[5];
    const float* w3    = (const float*)d_in[6];
    const float* b3    = (const float*)d_in[7];
    float* out = (float*)d_out;

    char* ws = (char*)d_ws;
    unsigned char* rowdil = (unsigned char*)ws;                         // NPIX
    unsigned char* dm     = (unsigned char*)(ws + (size_t)NPIX);        // NPIX
    unsigned char* rankb  = (unsigned char*)(ws + 2 * (size_t)NPIX);    // NPIX
    int* gsum             = (int*)(ws + 3 * (size_t)NPIX);              // NB
    int* goff             = (int*)(ws + 3 * (size_t)NPIX + NB * 4);     // NB
    unsigned short* w2f   = (unsigned short*)(ws + 3 * (size_t)NPIX + 2 * NB * 4); // 16384 bf16

    k_prep_w2<<<64, 256, 0, stream>>>(w2, w2f);
    k_rowdil <<<NPIX / 256, 256, 0, stream>>>(lr, rowdil);
    k_coldil <<<NB, 256, 0, stream>>>(rowdil, dm, rankb, gsum);
    k_scan   <<<1, 1024, 0, stream>>>(gsum, goff);
    k_mlp    <<<NMLP, 256, 0, stream>>>(image, lr, w1, b1, w2f, b2, w3, b3,
                                        dm, rankb, goff, out);
}